// Round 18
// baseline (3598.504 us; speedup 1.0000x reference)
//
#include <hip/hip_runtime.h>
#include <math.h>

// TemporalDecoder round 18: DIAGNOSTIC SPLIT of R17's persistent kernel into
// 9 dispatches (4x encL0-chunk, 4x encL1-chunk, 1x decode) so rocprof's
// per-dispatch durations decompose the ~11us/phase cost by segment type.
// c-state externalized to global (keyed by xcd,cs -> re-roster safe); barrier
// phases monotonic across dispatches (host passes bases). Code paths per
// segment byte-identical to R17; final barrier per dispatch dropped.

#define SS 128
#define NSTEPS 32
#define T 32

typedef __attribute__((ext_vector_type(8))) _Float16 f16x8;
typedef __attribute__((ext_vector_type(4))) float f32x4;

// ---------------- prep kernels ------------------------------------------------
__global__ __launch_bounds__(256) void xcvt(const float* __restrict__ x,
                                            ushort* __restrict__ xh, int n8) {
    int t = blockIdx.x * 256 + threadIdx.x;
    if (t >= n8) return;
    size_t i = (size_t)t * 8;
    float4 a = *(const float4*)(x + i), b = *(const float4*)(x + i + 4);
    union { _Float16 h[8]; uint4 u; } P;
    P.h[0] = (_Float16)a.x; P.h[1] = (_Float16)a.y;
    P.h[2] = (_Float16)a.z; P.h[3] = (_Float16)a.w;
    P.h[4] = (_Float16)b.x; P.h[5] = (_Float16)b.y;
    P.h[6] = (_Float16)b.z; P.h[7] = (_Float16)b.w;
    *(uint4*)(xh + i) = P.u;
}

__global__ __launch_bounds__(256) void wsplit5(
    const float* __restrict__ W_ih, const float* __restrict__ W_hh,
    const float* __restrict__ wcomb,
    ushort* __restrict__ wih0, ushort* __restrict__ whh0,
    ushort* __restrict__ wih1, ushort* __restrict__ whh1,
    ushort* __restrict__ wcmb)
{
    int f = blockIdx.x * 256 + threadIdx.x;      // 5 * 131072
    int mat = f >> 17;
    int t = f & 131071;
    int lane = t & 63;
    int kfg = (t >> 6) & 15;
    int wn = (t >> 10) & 3;
    int cs = t >> 12;
    int nloc = lane & 15;
    int g = nloc & 3, hcl = nloc >> 2;
    int n_W = g * 512 + cs * 16 + wn * 4 + hcl;
    int k = kfg * 32 + (lane >> 4) * 8;
    const float* src; ushort* dst;
    const size_t L1OFF = (size_t)2048 * 512;
    switch (mat) {
      case 0: src = W_ih + (size_t)n_W * 512 + k;         dst = wih0; break;
      case 1: src = W_hh + (size_t)n_W * 512 + k;         dst = whh0; break;
      case 2: src = W_ih + L1OFF + (size_t)n_W * 512 + k; dst = wih1; break;
      case 3: src = W_hh + L1OFF + (size_t)n_W * 512 + k; dst = whh1; break;
      default: src = wcomb + (size_t)n_W * 512 + k;       dst = wcmb; break;
    }
    float4 a = *(const float4*)src;
    float4 b = *(const float4*)(src + 4);
    float v[8] = {a.x, a.y, a.z, a.w, b.x, b.y, b.z, b.w};
    union { _Float16 h[8]; uint4 u; } Hi;
    #pragma unroll
    for (int j = 0; j < 8; ++j) Hi.h[j] = (_Float16)v[j];
    size_t b0 = (((size_t)cs * 4 + wn) * 16 + kfg) * 512 + lane * 8;
    *(uint4*)(dst + b0) = Hi.u;
}

__global__ __launch_bounds__(256) void wsplit_o(
    const float* __restrict__ W_out, ushort* __restrict__ wfO)
{
    int f = blockIdx.x * 256 + threadIdx.x;      // 32768
    int lane = f & 63;
    int kfg = (f >> 6) & 15;
    int cs = f >> 10;
    int col = cs * 16 + (lane & 15);
    int k = kfg * 32 + (lane >> 4) * 8;
    const float* src = W_out + (size_t)col * 512 + k;
    float4 a = *(const float4*)src;
    float4 b = *(const float4*)(src + 4);
    float v[8] = {a.x, a.y, a.z, a.w, b.x, b.y, b.z, b.w};
    union { _Float16 h[8]; uint4 u; } Hi;
    #pragma unroll
    for (int j = 0; j < 8; ++j) Hi.h[j] = (_Float16)v[j];
    size_t b0 = ((size_t)cs * 16 + kfg) * 512 + lane * 8;
    *(uint4*)(wfO + b0) = Hi.u;
}

__global__ __launch_bounds__(256) void gemm_wcomb(
    const float* __restrict__ A, const float* __restrict__ Bm, float* __restrict__ C)
{
    __shared__ float sAf[64][17];
    __shared__ float sBf[16][65];
    const int tid = threadIdx.x;
    const int tx = tid & 15, ty = tid >> 4;
    const int n0 = blockIdx.x * 64, h0 = blockIdx.y * 64;
    float acc[4][4] = {};
    #pragma unroll 1
    for (int k0 = 0; k0 < 512; k0 += 16) {
        __syncthreads();
        {
            int r = tid >> 2, c = (tid & 3) * 4;
            float4 v = *(const float4*)&A[(size_t)(n0 + r) * 512 + k0 + c];
            sAf[r][c] = v.x; sAf[r][c+1] = v.y; sAf[r][c+2] = v.z; sAf[r][c+3] = v.w;
        }
        {
            int r = tid >> 4, c = (tid & 15) * 4;
            float4 v = *(const float4*)&Bm[(size_t)(k0 + r) * 512 + h0 + c];
            sBf[r][c] = v.x; sBf[r][c+1] = v.y; sBf[r][c+2] = v.z; sBf[r][c+3] = v.w;
        }
        __syncthreads();
        #pragma unroll
        for (int kk = 0; kk < 16; ++kk)
            #pragma unroll
            for (int a_ = 0; a_ < 4; ++a_) {
                float av = sAf[ty + 16*a_][kk];
                #pragma unroll
                for (int b_ = 0; b_ < 4; ++b_)
                    acc[a_][b_] += av * sBf[kk][tx + 16*b_];
            }
    }
    #pragma unroll
    for (int a_ = 0; a_ < 4; ++a_)
        #pragma unroll
        for (int b_ = 0; b_ < 4; ++b_)
            C[(size_t)(n0 + ty + 16*a_) * 512 + h0 + tx + 16*b_] = acc[a_][b_];
}

__global__ __launch_bounds__(256) void bcomb_k(const float* __restrict__ Wih0,
                                               const float* __restrict__ bout,
                                               float* __restrict__ bc) {
    int n = blockIdx.x * 256 + threadIdx.x;
    float a = 0.f;
    for (int f = 0; f < 512; ++f) a += Wih0[(size_t)n * 512 + f] * bout[f];
    bc[n] = a;
}

// ---------------- device helpers ---------------------------------------------
__device__ __forceinline__ void wgbar() {
    __builtin_amdgcn_sched_barrier(0);
    asm volatile("s_waitcnt lgkmcnt(0)" ::: "memory");
    __builtin_amdgcn_s_barrier();
    asm volatile("" ::: "memory");
    __builtin_amdgcn_sched_barrier(0);
}

__device__ __forceinline__ void xbar(volatile unsigned* slots, unsigned phase, int cs) {
    __syncthreads();
    if (threadIdx.x == 0) slots[cs] = phase;
    if (threadIdx.x < 64) {
        for (;;) {
            unsigned v = (threadIdx.x < 32) ? slots[threadIdx.x] : phase;
            if (__all((int)(v >= phase))) break;
            __builtin_amdgcn_s_sleep(2);
        }
        asm volatile("buffer_inv" ::: "memory");
    }
    __syncthreads();
}

__device__ __forceinline__ void ldChunk(uint4 (&u)[4], const ushort* src,
                                        size_t ld, int k0) {
    const int t = threadIdx.x;
    const int row = t >> 3;
    const int cg0 = (t & 7) * 4;
    const ushort* s = src + (size_t)row * ld + k0 + cg0 * 8;
    #pragma unroll
    for (int q = 0; q < 4; ++q) u[q] = *(const uint4*)(s + q * 8);
}
__device__ __forceinline__ void wrChunk(const uint4 (&u)[4], ushort (*sAb)[256]) {
    const int t = threadIdx.x;
    const int row = t >> 3;
    const int cg0 = (t & 7) * 4;
    #pragma unroll
    for (int q = 0; q < 4; ++q) {
        int cg = cg0 + q;
        int slot = (cg & 24) | ((cg ^ row) & 7);
        *(uint4*)&sAb[row][slot * 8] = u[q];
    }
}

// ---------------- unified LSTM/fc step (identical to R17) ---------------------
template<bool PREX, bool BLDS, bool FC, bool CARRY>
static __device__ __forceinline__ void do_step(
    const ushort* A1, size_t ld1, const ushort* A2,
    const uint4 (*px)[4],
    const ushort* B1s, const ushort* B2s,
    ushort (*sW)[4][16][512], ushort (*sA)[32][256],
    float* cReg, float biasv, ushort* Hout, ushort* Hcarry,
    const ushort* wfO_cs, float bofc, float* outp, int s, int xrow0,
    int lane, int wn, int cs)
{
    const int lr = lane & 15, lq = lane >> 4;

    uint4 ur[3][4];
    if constexpr (PREX) {
        ldChunk(ur[0], A2, 512, 0);
        ldChunk(ur[1], A2, 512, 256);
    } else {
        ldChunk(ur[0], A1, ld1, 0);
        ldChunk(ur[1], A1, ld1, 256);
        ldChunk(ur[2], A2, 512, 0);
    }

    f16x8 pb1[16], pb2[16], po[16];
    if constexpr (!BLDS) {
        #pragma unroll
        for (int kfg = 0; kfg < 16; ++kfg)
            pb1[kfg] = *(const f16x8*)(B1s + (((size_t)wn) * 16 + kfg) * 512 + lane * 8);
    }
    if constexpr (FC) {
        if (wn < 2) {
            #pragma unroll
            for (int kfg = 0; kfg < 16; ++kfg)
                po[kfg] = *(const f16x8*)(wfO_cs + (size_t)kfg * 512 + lane * 8);
        }
    }

    f32x4 acch[2], fch;
    #pragma unroll
    for (int m = 0; m < 2; ++m) acch[m] = (f32x4){biasv, biasv, biasv, biasv};
    if constexpr (FC) fch = (f32x4){bofc, bofc, bofc, bofc};

    if constexpr (PREX) wrChunk(px[0], sA[0]);
    else                wrChunk(ur[0], sA[0]);

    #pragma unroll
    for (int c = 0; c < 4; ++c) {
        wgbar();
        if constexpr (!BLDS) {
            if (c == 1) {
                #pragma unroll
                for (int kfg = 0; kfg < 16; ++kfg)
                    pb2[kfg] = *(const f16x8*)(B2s + (((size_t)wn) * 16 + kfg) * 512 + lane * 8);
            }
        }
        if constexpr (!PREX) {
            if (c + 3 < 4) ldChunk(ur[(c + 3) % 3], A2, 512, 256);
        }
        if (c + 1 < 4) {
            if constexpr (PREX) {
                if (c + 1 == 1) wrChunk(px[1], sA[1]);
                else            wrChunk(ur[c + 1 - 2], sA[(c + 1) & 1]);
            } else {
                wrChunk(ur[(c + 1) % 3], sA[(c + 1) & 1]);
            }
        }
        const int bufc = c & 1;
        #pragma unroll
        for (int kf = 0; kf < 8; ++kf) {
            const int kfg = (c & 1) * 8 + kf;
            f16x8 bh;
            if constexpr (BLDS) {
                bh = *(const f16x8*)&sW[(c < 2) ? 0 : 1][wn][kfg][lane * 8];
            } else {
                bh = (c < 2) ? pb1[kfg] : pb2[kfg];
            }
            #pragma unroll
            for (int m = 0; m < 2; ++m) {
                int row = m * 16 + lr;
                int cg = kf * 4 + lq;
                int slot = (cg & 24) | ((cg ^ row) & 7);
                f16x8 a = *(const f16x8*)(&sA[bufc][row][0] + slot * 8);
                acch[m] = __builtin_amdgcn_mfma_f32_16x16x32_f16(a, bh, acch[m], 0, 0, 0);
            }
            if constexpr (FC) {
                if (wn < 2 && c < 2) {
                    int row = wn * 16 + lr;
                    int cg = kf * 4 + lq;
                    int slot = (cg & 24) | ((cg ^ row) & 7);
                    f16x8 a = *(const f16x8*)(&sA[bufc][row][0] + slot * 8);
                    fch = __builtin_amdgcn_mfma_f32_16x16x32_f16(a, po[kfg], fch, 0, 0, 0);
                }
            }
        }
    }

    const int nloc = lane & 15;
    const int g = nloc & 3;
    const int colb = cs * 16 + wn * 4;
    #pragma unroll
    for (int m = 0; m < 2; ++m) {
        #pragma unroll
        for (int j = 0; j < 4; ++j) {
            float v = acch[m][j];
            float s1 = __shfl_xor(v, 1, 64);
            float s2 = __shfl_xor(v, 2, 64);
            float s3 = __shfl_xor(v, 3, 64);
            float sel0 = v;
            auto selk = [&](int k) { return (k==0)?sel0:(k==1)?s1:(k==2)?s2:s3; };
            float pi = selk(g), pf = selk(g ^ 1), pg = selk(g ^ 2), po_ = selk(g ^ 3);
            float ig = 1.f / (1.f + __expf(-pi));
            float fg = 1.f / (1.f + __expf(-pf));
            float e2g = __expf(2.f * fminf(fmaxf(pg, -20.f), 20.f));
            float gg = (e2g - 1.f) / (e2g + 1.f);
            float og = 1.f / (1.f + __expf(-po_));
            float cn = fg * cReg[m * 4 + j] + ig * gg;
            cReg[m * 4 + j] = cn;
            float e2c = __expf(2.f * fminf(fmaxf(cn, -20.f), 20.f));
            float th = (e2c - 1.f) / (e2c + 1.f);
            float hn = og * th;
            union { _Float16 h; ushort u; } P; P.h = (_Float16)hn;
            int hb = (int)P.u;
            int base = lane & ~15;
            int b1 = __shfl(hb, base + 4, 64);
            int b2 = __shfl(hb, base + 8, 64);
            int b3 = __shfl(hb, base + 12, 64);
            if (lr == 0) {
                unsigned long long pk =
                    (unsigned long long)(unsigned)(hb & 0xFFFF)
                    | ((unsigned long long)(unsigned)(b1 & 0xFFFF) << 16)
                    | ((unsigned long long)(unsigned)(b2 & 0xFFFF) << 32)
                    | ((unsigned long long)(unsigned)(b3 & 0xFFFF) << 48);
                int row = m * 16 + lq * 4 + j;
                *(unsigned long long*)&Hout[(size_t)row * 512 + colb] = pk;
                if constexpr (CARRY)
                    *(unsigned long long*)&Hcarry[(size_t)row * 512 + colb] = pk;
            }
        }
    }
    if constexpr (FC) {
        if (wn < 2) {
            #pragma unroll
            for (int j = 0; j < 4; ++j) {
                float v = fch[j];
                int row = wn * 16 + lq * 4 + j;
                outp[((size_t)(xrow0 + row) * NSTEPS + s) * 512 + cs * 16 + lr] = v;
            }
        }
    }
}

// ---------------- segment kernel: MODE 0=encL0(ch), 1=encL1(ch), 2=decode -----
template<int MODE>
__global__ __launch_bounds__(256, 1) void kseg(
    const ushort* __restrict__ xh,
    const ushort* __restrict__ wih0f, const ushort* __restrict__ whh0f,
    const ushort* __restrict__ wih1f, const ushort* __restrict__ whh1f,
    const ushort* __restrict__ wcombf, const ushort* __restrict__ wfOf,
    const float* __restrict__ b_ih, const float* __restrict__ b_hh,
    const float* __restrict__ b_out, const float* __restrict__ bcomb,
    ushort* h0c_all, ushort* h1_all, float* out,
    float* cstA, float* cstB,
    unsigned* roster, unsigned* bar, unsigned phbase, int ch)
{
    __shared__ ushort sW[2][4][16][512];      // 128KB
    __shared__ ushort sA[2][32][256];         // 32KB

    const int tid = threadIdx.x;
    if (tid == 0) {
        int xid;
        asm volatile("s_getreg_b32 %0, hwreg(HW_REG_XCC_ID)" : "=s"(xid));
        xid &= 7;
        unsigned slot = atomicAdd(&roster[xid * 16], 1u) & 31u;
        *(int*)&sA[0][0][0] = xid * 32 + (int)slot;
    }
    __syncthreads();
    const int packed = *(const int*)&sA[0][0][0];
    __syncthreads();
    const int xcd = packed >> 5, cs = packed & 31;
    const int xrow0 = xcd * 32;
    const int wgid = xcd * 32 + cs;

    ushort* h0c = h0c_all + (size_t)xcd * 33 * 32 * 512;
    ushort* h1r = h1_all + (size_t)xcd * 2 * 32 * 512;
    volatile unsigned* slots = bar + xcd * 32;

    const int lane = tid & 63, wn = tid >> 6;
    const int nloc = lane & 15, g = nloc & 3, hcl = nloc >> 2;
    const int gcol = g * 512 + cs * 16 + wn * 4 + hcl;
    const float b0v = b_ih[gcol] + b_hh[gcol];
    const float b1v = b_ih[2048 + gcol] + b_hh[2048 + gcol];
    const float b0d = b0v + bcomb[gcol];
    const float bofc = b_out[cs * 16 + nloc];

    const ushort* wih0cs = wih0f + (size_t)cs * 32768;
    const ushort* whh0cs = whh0f + (size_t)cs * 32768;
    const ushort* wih1cs = wih1f + (size_t)cs * 32768;
    const ushort* whh1cs = whh1f + (size_t)cs * 32768;
    const ushort* wcombcs = wcombf + (size_t)cs * 32768;
    const ushort* wfOcs = wfOf + (size_t)cs * 8192;

    auto fillW2 = [&](const ushort* w1, const ushort* w2) {
        const uint4* s1 = (const uint4*)w1;
        const uint4* s2 = (const uint4*)w2;
        uint4* d1 = (uint4*)&sW[0][0][0][0];
        uint4* d2 = (uint4*)&sW[1][0][0][0];
        #pragma unroll 1
        for (int i = tid; i < 4096; i += 256) { d1[i] = s1[i]; d2[i] = s2[i]; }
        __syncthreads();
    };

    float* stA = cstA + ((size_t)wgid * 256 + tid) * 8;
    float* stB = cstB + ((size_t)wgid * 256 + tid) * 8;
    unsigned ph = phbase;

    uint4 px[2][4];
    auto pfA1 = [&](const ushort* a1, size_t ld) {
        ldChunk(px[0], a1, ld, 0);
        ldChunk(px[1], a1, ld, 256);
    };

    if constexpr (MODE == 0) {
        float c0[8];
        #pragma unroll
        for (int i = 0; i < 8; ++i) c0[i] = stA[i];
        fillW2(wih0cs, whh0cs);
        pfA1(xh + ((size_t)xrow0 * SS + ch * T) * 512, (size_t)SS * 512);
        #pragma unroll 1
        for (int ti = 0; ti < T; ++ti) {
            int t = ch * T + ti;
            if (ti == T - 1)
                do_step<true, true, false, true>(nullptr, 0,
                    h0c + (size_t)ti * 32 * 512, px, nullptr, nullptr, sW, sA,
                    c0, b0v, h0c + (size_t)(ti + 1) * 32 * 512, h0c,
                    nullptr, 0.f, nullptr, 0, xrow0, lane, wn, cs);
            else
                do_step<true, true, false, false>(nullptr, 0,
                    h0c + (size_t)ti * 32 * 512, px, nullptr, nullptr, sW, sA,
                    c0, b0v, h0c + (size_t)(ti + 1) * 32 * 512, nullptr,
                    nullptr, 0.f, nullptr, 0, xrow0, lane, wn, cs);
            if (ti + 1 < T) {
                pfA1(xh + ((size_t)xrow0 * SS + t + 1) * 512, (size_t)SS * 512);
                xbar(slots, ++ph, cs);
            }
        }
        #pragma unroll
        for (int i = 0; i < 8; ++i) stA[i] = c0[i];
    } else if constexpr (MODE == 1) {
        float c1[8];
        #pragma unroll
        for (int i = 0; i < 8; ++i) c1[i] = stB[i];
        fillW2(wih1cs, whh1cs);
        int cur = 0;
        pfA1(h0c + (size_t)1 * 32 * 512, 512);
        #pragma unroll 1
        for (int ti = 0; ti < T; ++ti) {
            do_step<true, true, false, false>(nullptr, 0,
                h1r + (size_t)cur * 32 * 512, px, nullptr, nullptr, sW, sA,
                c1, b1v, h1r + (size_t)(cur ^ 1) * 32 * 512, nullptr,
                nullptr, 0.f, nullptr, 0, xrow0, lane, wn, cs);
            cur ^= 1;
            if (ti + 1 < T) {
                pfA1(h0c + (size_t)(ti + 2) * 32 * 512, 512);
                xbar(slots, ++ph, cs);
            }
        }
        #pragma unroll
        for (int i = 0; i < 8; ++i) stB[i] = c1[i];
    } else {
        float c0[8], c1[8];
        #pragma unroll
        for (int i = 0; i < 8; ++i) { c0[i] = stA[i]; c1[i] = stB[i]; }
        fillW2(wih1cs, whh1cs);
        int cur = 0, c0i = 0;
        #pragma unroll 1
        for (int s = 0; s < NSTEPS; ++s) {
            do_step<false, false, true, false>(
                h1r + (size_t)cur * 32 * 512, 512,
                h0c + (size_t)c0i * 32 * 512, nullptr, wcombcs, whh0cs, sW, sA,
                c0, b0d, h0c + (size_t)(c0i ^ 1) * 32 * 512, nullptr,
                wfOcs, bofc, out, s, xrow0, lane, wn, cs);
            c0i ^= 1;
            if (s == NSTEPS - 1) break;
            xbar(slots, ++ph, cs);
            do_step<false, true, false, false>(
                h0c + (size_t)c0i * 32 * 512, 512,
                h1r + (size_t)cur * 32 * 512, nullptr, nullptr, nullptr, sW, sA,
                c1, b1v, h1r + (size_t)(cur ^ 1) * 32 * 512, nullptr,
                nullptr, 0.f, nullptr, 0, xrow0, lane, wn, cs);
            cur ^= 1;
            xbar(slots, ++ph, cs);
        }
    }
}

// ---------------- host ---------------------------------------------------------
extern "C" void kernel_launch(void* const* d_in, const int* in_sizes, int n_in,
                              void* d_out, int out_size, void* d_ws, size_t ws_size,
                              hipStream_t stream)
{
    const float* x     = (const float*)d_in[0];
    const float* W_ih  = (const float*)d_in[1];
    const float* W_hh  = (const float*)d_in[2];
    const float* b_ih  = (const float*)d_in[3];
    const float* b_hh  = (const float*)d_in[4];
    const float* W_out = (const float*)d_in[5];
    const float* b_out = (const float*)d_in[6];
    float* out = (float*)d_out;
    (void)n_in; (void)out_size; (void)ws_size;

    char* ws = (char*)d_ws;
    unsigned* roster = (unsigned*)(ws + 0);               // 9 regions x 512B
    unsigned* bar    = (unsigned*)(ws + 8192);            // 8 XCDs x 32 slots
    ushort* h0c_all  = (ushort*)(ws + 16384);             // 8,650,752
    ushort* h1_all   = (ushort*)(ws + 16384 + 8650752);   // 524,288
    float*  cstA     = (float*)(ws + 16384 + 8650752 + 524288);      // 2MB
    float*  cstB     = (float*)(ws + 16384 + 8650752 + 524288 + 2097152);
    const size_t ZB  = 16384 + 8650752 + 524288 + 2 * 2097152;  // 13,385,728
    ushort* wih0f  = (ushort*)(ws + ZB + 0 * 2097152);
    ushort* whh0f  = (ushort*)(ws + ZB + 1 * 2097152);
    ushort* wih1f  = (ushort*)(ws + ZB + 2 * 2097152);
    ushort* whh1f  = (ushort*)(ws + ZB + 3 * 2097152);
    ushort* wcombf = (ushort*)(ws + ZB + 4 * 2097152);
    ushort* wfOf   = (ushort*)(ws + ZB + 5 * 2097152);               // 512KB
    float*  wcomb  = (float*) (ws + ZB + 5 * 2097152 + 524288);      // 4MB
    float*  bcomb  = (float*) (ws + ZB + 5 * 2097152 + 524288 + 4194304);
    ushort* xh     = (ushort*)(ws + ZB + 5 * 2097152 + 524288 + 4194304 + 65536);
    // total ~64 MB

    (void)hipMemsetAsync(d_ws, 0, ZB, stream);
    {
        int n8 = (in_sizes[0] + 7) / 8;
        int blocks = (n8 + 255) / 256;
        xcvt<<<blocks, 256, 0, stream>>>(x, xh, n8);
    }
    gemm_wcomb<<<dim3(32, 8), 256, 0, stream>>>(W_ih, W_out, wcomb);
    bcomb_k<<<8, 256, 0, stream>>>(W_ih, b_out, bcomb);
    wsplit5<<<2560, 256, 0, stream>>>(W_ih, W_hh, wcomb,
                                      wih0f, whh0f, wih1f, whh1f, wcombf);
    wsplit_o<<<128, 256, 0, stream>>>(W_out, wfOf);

    unsigned phbase = 0;
    int disp = 0;
    for (int ch = 0; ch < 4; ++ch) {
        kseg<0><<<256, 256, 0, stream>>>(xh, wih0f, whh0f, wih1f, whh1f,
            wcombf, wfOf, b_ih, b_hh, b_out, bcomb, h0c_all, h1_all, out,
            cstA, cstB, roster + disp * 128, bar, phbase, ch);
        phbase += 31; ++disp;
        kseg<1><<<256, 256, 0, stream>>>(xh, wih0f, whh0f, wih1f, whh1f,
            wcombf, wfOf, b_ih, b_hh, b_out, bcomb, h0c_all, h1_all, out,
            cstA, cstB, roster + disp * 128, bar, phbase, ch);
        phbase += 31; ++disp;
    }
    kseg<2><<<256, 256, 0, stream>>>(xh, wih0f, whh0f, wih1f, whh1f,
        wcombf, wfOf, b_ih, b_hh, b_out, bcomb, h0c_all, h1_all, out,
        cstA, cstB, roster + disp * 128, bar, phbase, 0);
}

// Round 19
// 3028.754 us; speedup vs baseline: 1.1881x; 1.1881x over previous
//
#include <hip/hip_runtime.h>
#include <math.h>

// TemporalDecoder round 19: paired-XCD layer pipeline.
// R15-R18 proved per-phase overhead ~9-11us is invariant to sync mechanics ->
// cut PHASES: even XCD runs L0(t), odd XCD runs L1(t-1) concurrently (pair =
// 64 batch rows, M=64/CU). Encode: 256 -> 129 phases. Weights stay LDS-resident
// (same 64-col/CU slices). h0 handoff even->odd via agent stores (LLC);
// self-recurrence plain+buffer_inv (R16-proven). Decode: R16's proven 63-phase
// XCD-local structure after one-time h/c redistribution through global bufs.

#define SS 128
#define NSTEPS 32

typedef __attribute__((ext_vector_type(8))) _Float16 f16x8;
typedef __attribute__((ext_vector_type(4))) float f32x4;

#define AGENT __HIP_MEMORY_SCOPE_AGENT

__device__ __forceinline__ uint2 ld_agent_u2(const uint2* p) {
    return __hip_atomic_load(p, __ATOMIC_RELAXED, AGENT);
}
__device__ __forceinline__ void st_agent_u64(unsigned long long* p, unsigned long long v) {
    __hip_atomic_store(p, v, __ATOMIC_RELAXED, AGENT);
}
__device__ __forceinline__ void st_agent_f32(float* p, float v) {
    __hip_atomic_store(p, v, __ATOMIC_RELAXED, AGENT);
}
__device__ __forceinline__ float ld_agent_f32(const float* p) {
    return __hip_atomic_load(p, __ATOMIC_RELAXED, AGENT);
}

// ---------------- prep kernels (unchanged from R16) ---------------------------
__global__ __launch_bounds__(256) void xcvt(const float* __restrict__ x,
                                            ushort* __restrict__ xh, int n8) {
    int t = blockIdx.x * 256 + threadIdx.x;
    if (t >= n8) return;
    size_t i = (size_t)t * 8;
    float4 a = *(const float4*)(x + i), b = *(const float4*)(x + i + 4);
    union { _Float16 h[8]; uint4 u; } P;
    P.h[0] = (_Float16)a.x; P.h[1] = (_Float16)a.y;
    P.h[2] = (_Float16)a.z; P.h[3] = (_Float16)a.w;
    P.h[4] = (_Float16)b.x; P.h[5] = (_Float16)b.y;
    P.h[6] = (_Float16)b.z; P.h[7] = (_Float16)b.w;
    *(uint4*)(xh + i) = P.u;
}

__global__ __launch_bounds__(256) void wsplit5(
    const float* __restrict__ W_ih, const float* __restrict__ W_hh,
    const float* __restrict__ wcomb,
    ushort* __restrict__ wih0, ushort* __restrict__ whh0,
    ushort* __restrict__ wih1, ushort* __restrict__ whh1,
    ushort* __restrict__ wcmb)
{
    int f = blockIdx.x * 256 + threadIdx.x;
    int mat = f >> 17;
    int t = f & 131071;
    int lane = t & 63;
    int kfg = (t >> 6) & 15;
    int wn = (t >> 10) & 3;
    int cs = t >> 12;
    int nloc = lane & 15;
    int g = nloc & 3, hcl = nloc >> 2;
    int n_W = g * 512 + cs * 16 + wn * 4 + hcl;
    int k = kfg * 32 + (lane >> 4) * 8;
    const float* src; ushort* dst;
    const size_t L1OFF = (size_t)2048 * 512;
    switch (mat) {
      case 0: src = W_ih + (size_t)n_W * 512 + k;         dst = wih0; break;
      case 1: src = W_hh + (size_t)n_W * 512 + k;         dst = whh0; break;
      case 2: src = W_ih + L1OFF + (size_t)n_W * 512 + k; dst = wih1; break;
      case 3: src = W_hh + L1OFF + (size_t)n_W * 512 + k; dst = whh1; break;
      default: src = wcomb + (size_t)n_W * 512 + k;       dst = wcmb; break;
    }
    float4 a = *(const float4*)src;
    float4 b = *(const float4*)(src + 4);
    float v[8] = {a.x, a.y, a.z, a.w, b.x, b.y, b.z, b.w};
    union { _Float16 h[8]; uint4 u; } Hi;
    #pragma unroll
    for (int j = 0; j < 8; ++j) Hi.h[j] = (_Float16)v[j];
    size_t b0 = (((size_t)cs * 4 + wn) * 16 + kfg) * 512 + lane * 8;
    *(uint4*)(dst + b0) = Hi.u;
}

__global__ __launch_bounds__(256) void wsplit_o(
    const float* __restrict__ W_out, ushort* __restrict__ wfO)
{
    int f = blockIdx.x * 256 + threadIdx.x;
    int lane = f & 63;
    int kfg = (f >> 6) & 15;
    int cs = f >> 10;
    int col = cs * 16 + (lane & 15);
    int k = kfg * 32 + (lane >> 4) * 8;
    const float* src = W_out + (size_t)col * 512 + k;
    float4 a = *(const float4*)src;
    float4 b = *(const float4*)(src + 4);
    float v[8] = {a.x, a.y, a.z, a.w, b.x, b.y, b.z, b.w};
    union { _Float16 h[8]; uint4 u; } Hi;
    #pragma unroll
    for (int j = 0; j < 8; ++j) Hi.h[j] = (_Float16)v[j];
    size_t b0 = ((size_t)cs * 16 + kfg) * 512 + lane * 8;
    *(uint4*)(wfO + b0) = Hi.u;
}

__global__ __launch_bounds__(256) void gemm_wcomb(
    const float* __restrict__ A, const float* __restrict__ Bm, float* __restrict__ C)
{
    __shared__ float sAf[64][17];
    __shared__ float sBf[16][65];
    const int tid = threadIdx.x;
    const int tx = tid & 15, ty = tid >> 4;
    const int n0 = blockIdx.x * 64, h0 = blockIdx.y * 64;
    float acc[4][4] = {};
    #pragma unroll 1
    for (int k0 = 0; k0 < 512; k0 += 16) {
        __syncthreads();
        {
            int r = tid >> 2, c = (tid & 3) * 4;
            float4 v = *(const float4*)&A[(size_t)(n0 + r) * 512 + k0 + c];
            sAf[r][c] = v.x; sAf[r][c+1] = v.y; sAf[r][c+2] = v.z; sAf[r][c+3] = v.w;
        }
        {
            int r = tid >> 4, c = (tid & 15) * 4;
            float4 v = *(const float4*)&Bm[(size_t)(k0 + r) * 512 + h0 + c];
            sBf[r][c] = v.x; sBf[r][c+1] = v.y; sBf[r][c+2] = v.z; sBf[r][c+3] = v.w;
        }
        __syncthreads();
        #pragma unroll
        for (int kk = 0; kk < 16; ++kk)
            #pragma unroll
            for (int a_ = 0; a_ < 4; ++a_) {
                float av = sAf[ty + 16*a_][kk];
                #pragma unroll
                for (int b_ = 0; b_ < 4; ++b_)
                    acc[a_][b_] += av * sBf[kk][tx + 16*b_];
            }
    }
    #pragma unroll
    for (int a_ = 0; a_ < 4; ++a_)
        #pragma unroll
        for (int b_ = 0; b_ < 4; ++b_)
            C[(size_t)(n0 + ty + 16*a_) * 512 + h0 + tx + 16*b_] = acc[a_][b_];
}

__global__ __launch_bounds__(256) void bcomb_k(const float* __restrict__ Wih0,
                                               const float* __restrict__ bout,
                                               float* __restrict__ bc) {
    int n = blockIdx.x * 256 + threadIdx.x;
    float a = 0.f;
    for (int f = 0; f < 512; ++f) a += Wih0[(size_t)n * 512 + f] * bout[f];
    bc[n] = a;
}

// ---------------- sync helpers ------------------------------------------------
__device__ __forceinline__ void wgbar() {
    __builtin_amdgcn_sched_barrier(0);
    asm volatile("s_waitcnt lgkmcnt(0)" ::: "memory");
    __builtin_amdgcn_s_barrier();
    asm volatile("" ::: "memory");
    __builtin_amdgcn_sched_barrier(0);
}

// pair barrier: 64 sc1 slots (2 XCDs x 32 WGs), wave0 scans, inv after detect
__device__ __forceinline__ void pbar(unsigned* slots, unsigned phase, int myslot) {
    __syncthreads();
    if (threadIdx.x == 0)
        __hip_atomic_store(&slots[myslot], phase, __ATOMIC_RELAXED, AGENT);
    if (threadIdx.x < 64) {
        for (;;) {
            unsigned v = __hip_atomic_load(&slots[threadIdx.x], __ATOMIC_RELAXED, AGENT);
            if (__all((int)(v >= phase))) break;
            __builtin_amdgcn_s_sleep(2);
        }
        asm volatile("buffer_inv" ::: "memory");
    }
    __syncthreads();
}

// XCD-local barrier (R16-proven): plain slots + inv after detect
__device__ __forceinline__ void xbar(volatile unsigned* slots, unsigned phase, int cs) {
    __syncthreads();
    if (threadIdx.x == 0) slots[cs] = phase;
    if (threadIdx.x < 64) {
        for (;;) {
            unsigned v = (threadIdx.x < 32) ? slots[threadIdx.x] : phase;
            if (__all((int)(v >= phase))) break;
            __builtin_amdgcn_s_sleep(2);
        }
        asm volatile("buffer_inv" ::: "memory");
    }
    __syncthreads();
}

// ---------------- M=64 staging (encode) ---------------------------------------
__device__ __forceinline__ void ldC64P(uint4 (&u)[4], const ushort* src,
                                       size_t ld, int k0) {
    const int t = threadIdx.x;
    const int row = t >> 2;
    const int cg0 = (t & 3) * 4;
    const ushort* s = src + (size_t)row * ld + k0 + cg0 * 8;
    #pragma unroll
    for (int q = 0; q < 4; ++q) u[q] = *(const uint4*)(s + q * 8);
}
__device__ __forceinline__ void ldC64A(uint4 (&u)[4], const ushort* src,
                                       size_t ld, int k0) {
    const int t = threadIdx.x;
    const int row = t >> 2;
    const int cg0 = (t & 3) * 4;
    const ushort* s = src + (size_t)row * ld + k0 + cg0 * 8;
    #pragma unroll
    for (int q = 0; q < 4; ++q) {
        uint2 a = ld_agent_u2((const uint2*)(s + q * 8));
        uint2 b = ld_agent_u2((const uint2*)(s + q * 8) + 1);
        u[q].x = a.x; u[q].y = a.y; u[q].z = b.x; u[q].w = b.y;
    }
}
__device__ __forceinline__ void wrC64(const uint4 (&u)[4], ushort (*sAb)[128]) {
    const int t = threadIdx.x;
    const int row = t >> 2;
    const int cg0 = (t & 3) * 4;
    #pragma unroll
    for (int q = 0; q < 4; ++q) {
        int cg = cg0 + q;
        int slot = (cg & 8) | ((cg ^ row) & 7);
        *(uint4*)&sAb[row][slot * 8] = u[q];
    }
}

// ---------------- encode step (M=64): gates = b + Wih@A1 + Whh@A2 -------------
template<bool A1AG>
static __device__ __forceinline__ void enc_step(
    const ushort* A1, size_t ld1, const ushort* A2loc,
    ushort (*sW)[4][16][512], ushort (*sA)[64][128],
    float* cReg, float biasv,
    ushort* HoutLoc, ushort* HoutHand,
    int lane, int wn, int cs)
{
    const int lr = lane & 15, lq = lane >> 4;
    uint4 ur[3][4];
    auto ldc = [&](int c) {
        if (c < 4) {
            if constexpr (A1AG) ldC64A(ur[c % 3], A1, ld1, c * 128);
            else                ldC64P(ur[c % 3], A1, ld1, c * 128);
        } else {
            ldC64P(ur[c % 3], A2loc, 512, (c - 4) * 128);
        }
    };
    ldc(0); ldc(1); ldc(2);

    f32x4 acch[4];
    #pragma unroll
    for (int m = 0; m < 4; ++m) acch[m] = (f32x4){biasv, biasv, biasv, biasv};

    wrC64(ur[0], sA[0]);
    #pragma unroll
    for (int c = 0; c < 8; ++c) {
        wgbar();
        if (c + 3 < 8) ldc(c + 3);
        if (c + 1 < 8) wrC64(ur[(c + 1) % 3], sA[(c + 1) & 1]);
        const int bufc = c & 1, mat = c >> 2;
        #pragma unroll
        for (int kf = 0; kf < 4; ++kf) {
            const int kfg = (c & 3) * 4 + kf;
            f16x8 bh = *(const f16x8*)&sW[mat][wn][kfg][lane * 8];
            #pragma unroll
            for (int mf = 0; mf < 4; ++mf) {
                int row = mf * 16 + lr;
                int cg = kf * 4 + lq;
                int slot = (cg & 8) | ((cg ^ row) & 7);
                f16x8 a = *(const f16x8*)(&sA[bufc][row][0] + slot * 8);
                acch[mf] = __builtin_amdgcn_mfma_f32_16x16x32_f16(a, bh, acch[mf], 0, 0, 0);
            }
        }
    }

    const int nloc = lane & 15;
    const int g = nloc & 3;
    const int colb = cs * 16 + wn * 4;
    #pragma unroll
    for (int mf = 0; mf < 4; ++mf) {
        #pragma unroll
        for (int j = 0; j < 4; ++j) {
            float v = acch[mf][j];
            float s1 = __shfl_xor(v, 1, 64);
            float s2 = __shfl_xor(v, 2, 64);
            float s3 = __shfl_xor(v, 3, 64);
            float sel0 = v;
            auto selk = [&](int k) { return (k==0)?sel0:(k==1)?s1:(k==2)?s2:s3; };
            float pi = selk(g), pf = selk(g ^ 1), pg = selk(g ^ 2), po_ = selk(g ^ 3);
            float ig = 1.f / (1.f + __expf(-pi));
            float fg = 1.f / (1.f + __expf(-pf));
            float e2g = __expf(2.f * fminf(fmaxf(pg, -20.f), 20.f));
            float gg = (e2g - 1.f) / (e2g + 1.f);
            float og = 1.f / (1.f + __expf(-po_));
            float cn = fg * cReg[mf * 4 + j] + ig * gg;
            cReg[mf * 4 + j] = cn;
            float e2c = __expf(2.f * fminf(fmaxf(cn, -20.f), 20.f));
            float th = (e2c - 1.f) / (e2c + 1.f);
            float hn = og * th;
            union { _Float16 h; ushort u; } P; P.h = (_Float16)hn;
            int hb = (int)P.u;
            int base = lane & ~15;
            int b1 = __shfl(hb, base + 4, 64);
            int b2 = __shfl(hb, base + 8, 64);
            int b3 = __shfl(hb, base + 12, 64);
            if (lr == 0) {
                unsigned long long pk =
                    (unsigned long long)(unsigned)(hb & 0xFFFF)
                    | ((unsigned long long)(unsigned)(b1 & 0xFFFF) << 16)
                    | ((unsigned long long)(unsigned)(b2 & 0xFFFF) << 32)
                    | ((unsigned long long)(unsigned)(b3 & 0xFFFF) << 48);
                int row = mf * 16 + lq * 4 + j;
                *(unsigned long long*)&HoutLoc[(size_t)row * 512 + colb] = pk;
                st_agent_u64((unsigned long long*)&HoutHand[(size_t)row * 512 + colb], pk);
            }
        }
    }
}

// ---------------- M=32 staging + step (decode; R16-proven paths) --------------
__device__ __forceinline__ void ldC32(uint4 (&u)[4], const ushort* src,
                                      size_t ld, int k0) {
    const int t = threadIdx.x;
    const int row = t >> 3;
    const int cg0 = (t & 7) * 4;
    const ushort* s = src + (size_t)row * ld + k0 + cg0 * 8;
    #pragma unroll
    for (int q = 0; q < 4; ++q) u[q] = *(const uint4*)(s + q * 8);
}
__device__ __forceinline__ void wrC32(const uint4 (&u)[4], ushort (*sAb)[256]) {
    const int t = threadIdx.x;
    const int row = t >> 3;
    const int cg0 = (t & 7) * 4;
    #pragma unroll
    for (int q = 0; q < 4; ++q) {
        int cg = cg0 + q;
        int slot = (cg & 24) | ((cg ^ row) & 7);
        *(uint4*)&sAb[row][slot * 8] = u[q];
    }
}

template<bool BLDS, bool FC>
static __device__ __forceinline__ void dec_step(
    const ushort* A1, const ushort* A2,
    const ushort* B1s, const ushort* B2s,
    ushort (*sW)[4][16][512], ushort (*sA)[32][256],
    float* cReg, float biasv, ushort* Hout,
    const ushort* wfO_cs, float bofc, float* outp, int s, int xrow0,
    int lane, int wn, int cs)
{
    const int lr = lane & 15, lq = lane >> 4;
    uint4 ur[3][4];
    ldC32(ur[0], A1, 512, 0);
    ldC32(ur[1], A1, 512, 256);
    ldC32(ur[2], A2, 512, 0);

    f16x8 pb1[16], pb2[16], po[16];
    if constexpr (!BLDS) {
        #pragma unroll
        for (int kfg = 0; kfg < 16; ++kfg)
            pb1[kfg] = *(const f16x8*)(B1s + (((size_t)wn) * 16 + kfg) * 512 + lane * 8);
    }
    if constexpr (FC) {
        if (wn < 2) {
            #pragma unroll
            for (int kfg = 0; kfg < 16; ++kfg)
                po[kfg] = *(const f16x8*)(wfO_cs + (size_t)kfg * 512 + lane * 8);
        }
    }

    f32x4 acch[2], fch;
    #pragma unroll
    for (int m = 0; m < 2; ++m) acch[m] = (f32x4){biasv, biasv, biasv, biasv};
    if constexpr (FC) fch = (f32x4){bofc, bofc, bofc, bofc};

    wrC32(ur[0], sA[0]);
    #pragma unroll
    for (int c = 0; c < 4; ++c) {
        wgbar();
        if constexpr (!BLDS) {
            if (c == 1) {
                #pragma unroll
                for (int kfg = 0; kfg < 16; ++kfg)
                    pb2[kfg] = *(const f16x8*)(B2s + (((size_t)wn) * 16 + kfg) * 512 + lane * 8);
            }
        }
        if (c + 3 < 4) ldC32(ur[(c + 3) % 3], A2, 512, 256);
        if (c + 1 < 4) wrC32(ur[(c + 1) % 3], sA[(c + 1) & 1]);
        const int bufc = c & 1;
        #pragma unroll
        for (int kf = 0; kf < 8; ++kf) {
            const int kfg = (c & 1) * 8 + kf;
            f16x8 bh;
            if constexpr (BLDS) bh = *(const f16x8*)&sW[(c < 2) ? 0 : 1][wn][kfg][lane * 8];
            else                bh = (c < 2) ? pb1[kfg] : pb2[kfg];
            #pragma unroll
            for (int m = 0; m < 2; ++m) {
                int row = m * 16 + lr;
                int cg = kf * 4 + lq;
                int slot = (cg & 24) | ((cg ^ row) & 7);
                f16x8 a = *(const f16x8*)(&sA[bufc][row][0] + slot * 8);
                acch[m] = __builtin_amdgcn_mfma_f32_16x16x32_f16(a, bh, acch[m], 0, 0, 0);
            }
            if constexpr (FC) {
                if (wn < 2 && c < 2) {
                    int row = wn * 16 + lr;
                    int cg = kf * 4 + lq;
                    int slot = (cg & 24) | ((cg ^ row) & 7);
                    f16x8 a = *(const f16x8*)(&sA[bufc][row][0] + slot * 8);
                    fch = __builtin_amdgcn_mfma_f32_16x16x32_f16(a, po[kfg], fch, 0, 0, 0);
                }
            }
        }
    }

    const int nloc = lane & 15;
    const int g = nloc & 3;
    const int colb = cs * 16 + wn * 4;
    #pragma unroll
    for (int m = 0; m < 2; ++m) {
        #pragma unroll
        for (int j = 0; j < 4; ++j) {
            float v = acch[m][j];
            float s1 = __shfl_xor(v, 1, 64);
            float s2 = __shfl_xor(v, 2, 64);
            float s3 = __shfl_xor(v, 3, 64);
            float sel0 = v;
            auto selk = [&](int k) { return (k==0)?sel0:(k==1)?s1:(k==2)?s2:s3; };
            float pi = selk(g), pf = selk(g ^ 1), pg = selk(g ^ 2), po_ = selk(g ^ 3);
            float ig = 1.f / (1.f + __expf(-pi));
            float fg = 1.f / (1.f + __expf(-pf));
            float e2g = __expf(2.f * fminf(fmaxf(pg, -20.f), 20.f));
            float gg = (e2g - 1.f) / (e2g + 1.f);
            float og = 1.f / (1.f + __expf(-po_));
            float cn = fg * cReg[m * 4 + j] + ig * gg;
            cReg[m * 4 + j] = cn;
            float e2c = __expf(2.f * fminf(fmaxf(cn, -20.f), 20.f));
            float th = (e2c - 1.f) / (e2c + 1.f);
            float hn = og * th;
            union { _Float16 h; ushort u; } P; P.h = (_Float16)hn;
            int hb = (int)P.u;
            int base = lane & ~15;
            int b1 = __shfl(hb, base + 4, 64);
            int b2 = __shfl(hb, base + 8, 64);
            int b3 = __shfl(hb, base + 12, 64);
            if (lr == 0) {
                unsigned long long pk =
                    (unsigned long long)(unsigned)(hb & 0xFFFF)
                    | ((unsigned long long)(unsigned)(b1 & 0xFFFF) << 16)
                    | ((unsigned long long)(unsigned)(b2 & 0xFFFF) << 32)
                    | ((unsigned long long)(unsigned)(b3 & 0xFFFF) << 48);
                int row = m * 16 + lq * 4 + j;
                *(unsigned long long*)&Hout[(size_t)row * 512 + colb] = pk;
            }
        }
    }
    if constexpr (FC) {
        if (wn < 2) {
            #pragma unroll
            for (int j = 0; j < 4; ++j) {
                float v = fch[j];
                int row = wn * 16 + lq * 4 + j;
                outp[((size_t)(xrow0 + row) * NSTEPS + s) * 512 + cs * 16 + lr] = v;
            }
        }
    }
}

// ---------------- persistent kernel ------------------------------------------
__global__ __launch_bounds__(256, 1) void persist(
    const ushort* __restrict__ xh,
    const ushort* __restrict__ wih0f, const ushort* __restrict__ whh0f,
    const ushort* __restrict__ wih1f, const ushort* __restrict__ whh1f,
    const ushort* __restrict__ wcombf, const ushort* __restrict__ wfOf,
    const float* __restrict__ b_ih, const float* __restrict__ b_hh,
    const float* __restrict__ b_out, const float* __restrict__ bcomb,
    ushort* h0loc_a, ushort* h0hand_a, ushort* h1loc_a, ushort* h1hand_a,
    ushort* h0dec_a, ushort* h1dec_a, float* c0g, float* c1g,
    float* out, unsigned* roster, unsigned* pairbar, unsigned* xcdbar)
{
    __shared__ ushort sW[2][4][16][512];      // 128KB
    __shared__ ushort sA[2][64][128];         // 32KB (encode shape)

    const int tid = threadIdx.x;
    if (tid == 0) {
        int xid;
        asm volatile("s_getreg_b32 %0, hwreg(HW_REG_XCC_ID)" : "=s"(xid));
        xid &= 7;
        unsigned slot = atomicAdd(&roster[xid * 16], 1u) & 31u;
        *(int*)&sA[0][0][0] = xid * 32 + (int)slot;
    }
    __syncthreads();
    const int packed = *(const int*)&sA[0][0][0];
    __syncthreads();
    const int xcd = packed >> 5, cs = packed & 31;
    const int pair = xcd >> 1, role = xcd & 1;

    const int lane = tid & 63, wn = tid >> 6;
    const int nloc = lane & 15, g = nloc & 3, hcl = nloc >> 2;
    const int gcol = g * 512 + cs * 16 + wn * 4 + hcl;
    const float b0v = b_ih[gcol] + b_hh[gcol];
    const float b1v = b_ih[2048 + gcol] + b_hh[2048 + gcol];
    const float b0d = b0v + bcomb[gcol];
    const float bofc = b_out[cs * 16 + nloc];
    const int hcol = cs * 16 + wn * 4 + hcl;   // this lane's (redundant) hcol

    const ushort* wih0cs = wih0f + (size_t)cs * 32768;
    const ushort* whh0cs = whh0f + (size_t)cs * 32768;
    const ushort* wih1cs = wih1f + (size_t)cs * 32768;
    const ushort* whh1cs = whh1f + (size_t)cs * 32768;
    const ushort* wcombcs = wcombf + (size_t)cs * 32768;
    const ushort* wfOcs = wfOf + (size_t)cs * 8192;

    auto fillW2 = [&](const ushort* w1, const ushort* w2) {
        const uint4* s1 = (const uint4*)w1;
        const uint4* s2 = (const uint4*)w2;
        uint4* d1 = (uint4*)&sW[0][0][0][0];
        uint4* d2 = (uint4*)&sW[1][0][0][0];
        #pragma unroll 1
        for (int i = tid; i < 4096; i += 256) { d1[i] = s1[i]; d2[i] = s2[i]; }
        __syncthreads();
    };

    // per-pair buffers: [2 slots][64][512]
    const size_t PB = (size_t)2 * 64 * 512;
    ushort* h0loc  = h0loc_a  + (size_t)pair * PB;
    ushort* h0hand = h0hand_a + (size_t)pair * PB;
    ushort* h1loc  = h1loc_a  + (size_t)pair * PB;
    ushort* h1hand = h1hand_a + (size_t)pair * PB;
    unsigned* pslots = pairbar + pair * 64;
    const int myslot = role * 32 + cs;

    float cR[16];
    #pragma unroll
    for (int i = 0; i < 16; ++i) cR[i] = 0.f;
    unsigned ph = 0;

    // ---- encode: 129 pair-phases; even: L0(p) p<128; odd: L1(p-1) p>=1 ----
    if (role == 0) fillW2(wih0cs, whh0cs);
    else           fillW2(wih1cs, whh1cs);
    #pragma unroll 1
    for (int p = 0; p <= SS; ++p) {
        if (role == 0) {
            if (p < SS) {
                int t = p, rs = t & 1, wsl = rs ^ 1;
                enc_step<false>(xh + (((size_t)pair * 64) * SS + t) * 512, (size_t)SS * 512,
                    h0loc + (size_t)rs * 64 * 512, sW, sA, cR, b0v,
                    h0loc + (size_t)wsl * 64 * 512, h0hand + (size_t)wsl * 64 * 512,
                    lane, wn, cs);
            }
        } else {
            if (p >= 1) {
                int t = p - 1, a1s = (t & 1) ^ 1, rs = t & 1, wsl = rs ^ 1;
                enc_step<true>(h0hand + (size_t)a1s * 64 * 512, 512,
                    h1loc + (size_t)rs * 64 * 512, sW, sA, cR, b1v,
                    h1loc + (size_t)wsl * 64 * 512, h1hand + (size_t)wsl * 64 * 512,
                    lane, wn, cs);
            }
        }
        pbar(pslots, ++ph, myslot);
    }

    // ---- transition: dump c-state keyed by (global row, hcol) ----
    {
        float* cg_ = (role == 0) ? c0g : c1g;
        if (g == 0) {
            #pragma unroll
            for (int mf = 0; mf < 4; ++mf)
                #pragma unroll
                for (int j = 0; j < 4; ++j) {
                    int rowg = pair * 64 + mf * 16 + (lane >> 4) * 4 + j;
                    st_agent_f32(&cg_[(size_t)rowg * 512 + hcol], cR[mf * 4 + j]);
                }
        }
        pbar(pslots, ++ph, myslot);
    }

    // ---- decode init: redistribute to per-XCD 32-row slices ----
    const int xrow0 = xcd * 32;
    const int rowoff = role * 32;   // offset within pair's 64 rows
    ushort* h0dec = h0dec_a + (size_t)xcd * 2 * 32 * 512;
    ushort* h1dec = h1dec_a + (size_t)xcd * 2 * 32 * 512;
    volatile unsigned* xslots = xcdbar + xcd * 32;
    {
        const uint2* s0 = (const uint2*)(h0hand + (size_t)0 * 64 * 512 + (size_t)rowoff * 512);
        const uint2* s1 = (const uint2*)(h1hand + (size_t)0 * 64 * 512 + (size_t)rowoff * 512);
        uint2* d0 = (uint2*)h0dec;          // slot 0
        uint2* d1 = (uint2*)h1dec;          // slot 0
        #pragma unroll 1
        for (int i = tid; i < 4096; i += 256) {
            d0[i] = ld_agent_u2(s0 + i);
            d1[i] = ld_agent_u2(s1 + i);
        }
    }
    float c0[8], c1[8];
    #pragma unroll
    for (int mf = 0; mf < 2; ++mf)
        #pragma unroll
        for (int j = 0; j < 4; ++j) {
            int rowg = xrow0 + mf * 16 + (lane >> 4) * 4 + j;
            c0[mf * 4 + j] = ld_agent_f32(&c0g[(size_t)rowg * 512 + hcol]);
            c1[mf * 4 + j] = ld_agent_f32(&c1g[(size_t)rowg * 512 + hcol]);
        }
    fillW2(wih1cs, whh1cs);
    unsigned dph = 0;
    xbar(xslots, ++dph, cs);

    // ---- decode: R16 structure, 63 local phases ----
    ushort (*sA32)[32][256] = (ushort (*)[32][256])sA;
    int cur = 0, c0i = 0;
    #pragma unroll 1
    for (int s = 0; s < NSTEPS; ++s) {
        dec_step<false, true>(
            h1dec + (size_t)cur * 32 * 512,
            h0dec + (size_t)c0i * 32 * 512,
            wcombcs, whh0cs, sW, sA32,
            c0, b0d, h0dec + (size_t)(c0i ^ 1) * 32 * 512,
            wfOcs, bofc, out, s, xrow0, lane, wn, cs);
        xbar(xslots, ++dph, cs);
        c0i ^= 1;
        if (s == NSTEPS - 1) break;
        dec_step<true, false>(
            h0dec + (size_t)c0i * 32 * 512,
            h1dec + (size_t)cur * 32 * 512,
            nullptr, nullptr, sW, sA32,
            c1, b1v, h1dec + (size_t)(cur ^ 1) * 32 * 512,
            nullptr, 0.f, nullptr, 0, xrow0, lane, wn, cs);
        cur ^= 1;
        xbar(xslots, ++dph, cs);
    }
}

// ---------------- host ---------------------------------------------------------
extern "C" void kernel_launch(void* const* d_in, const int* in_sizes, int n_in,
                              void* d_out, int out_size, void* d_ws, size_t ws_size,
                              hipStream_t stream)
{
    const float* x     = (const float*)d_in[0];
    const float* W_ih  = (const float*)d_in[1];
    const float* W_hh  = (const float*)d_in[2];
    const float* b_ih  = (const float*)d_in[3];
    const float* b_hh  = (const float*)d_in[4];
    const float* W_out = (const float*)d_in[5];
    const float* b_out = (const float*)d_in[6];
    float* out = (float*)d_out;
    (void)n_in; (void)out_size; (void)ws_size;

    char* ws = (char*)d_ws;
    unsigned* roster  = (unsigned*)(ws + 0);             // 512B
    unsigned* pairbar = (unsigned*)(ws + 512);           // 4*64*4 = 1KB
    unsigned* xcdbar  = (unsigned*)(ws + 2048);          // 8*32*4 = 1KB
    size_t off = 4096;
    ushort* h0loc_a  = (ushort*)(ws + off); off += 524288;
    ushort* h0hand_a = (ushort*)(ws + off); off += 524288;
    ushort* h1loc_a  = (ushort*)(ws + off); off += 524288;
    ushort* h1hand_a = (ushort*)(ws + off); off += 524288;
    ushort* h0dec_a  = (ushort*)(ws + off); off += 524288;
    ushort* h1dec_a  = (ushort*)(ws + off); off += 524288;
    float*  c0g      = (float*)(ws + off);  off += 524288;
    float*  c1g      = (float*)(ws + off);  off += 524288;
    const size_t ZB = off;                               // ~4.2MB zeroed
    ushort* wih0f  = (ushort*)(ws + ZB + 0 * 2097152);
    ushort* whh0f  = (ushort*)(ws + ZB + 1 * 2097152);
    ushort* wih1f  = (ushort*)(ws + ZB + 2 * 2097152);
    ushort* whh1f  = (ushort*)(ws + ZB + 3 * 2097152);
    ushort* wcombf = (ushort*)(ws + ZB + 4 * 2097152);
    ushort* wfOf   = (ushort*)(ws + ZB + 5 * 2097152);               // 512KB
    float*  wcomb  = (float*) (ws + ZB + 5 * 2097152 + 524288);      // 4MB
    float*  bcomb  = (float*) (ws + ZB + 5 * 2097152 + 524288 + 4194304);
    ushort* xh     = (ushort*)(ws + ZB + 5 * 2097152 + 524288 + 4194304 + 65536);

    (void)hipMemsetAsync(d_ws, 0, ZB, stream);
    {
        int n8 = (in_sizes[0] + 7) / 8;
        int blocks = (n8 + 255) / 256;
        xcvt<<<blocks, 256, 0, stream>>>(x, xh, n8);
    }
    gemm_wcomb<<<dim3(32, 8), 256, 0, stream>>>(W_ih, W_out, wcomb);
    bcomb_k<<<8, 256, 0, stream>>>(W_ih, b_out, bcomb);
    wsplit5<<<2560, 256, 0, stream>>>(W_ih, W_hh, wcomb,
                                      wih0f, whh0f, wih1f, whh1f, wcombf);
    wsplit_o<<<128, 256, 0, stream>>>(W_out, wfOf);

    persist<<<dim3(256), dim3(256), 0, stream>>>(
        xh, wih0f, whh0f, wih1f, whh1f, wcombf, wfOf,
        b_ih, b_hh, b_out, bcomb,
        h0loc_a, h0hand_a, h1loc_a, h1hand_a,
        h0dec_a, h1dec_a, c0g, c1g,
        out, roster, pairbar, xcdbar);
}